// Round 7
// baseline (219.403 us; speedup 1.0000x reference)
//
#include <hip/hip_runtime.h>
#include <hip/hip_bf16.h>
#include <stdint.h>

#define IN_F   4096
#define OUT_F  4096
#define M_ROWS 2048
#define NG     32
#define GRP    128

typedef __bf16 bf16x8 __attribute__((ext_vector_type(8)));
typedef float  f32x4  __attribute__((ext_vector_type(4)));

typedef const void __attribute__((address_space(1))) cv_g;
typedef void       __attribute__((address_space(3))) v_l;

__device__ __forceinline__ void async16(const void* g, void* l) {
  // global -> LDS DMA, 16B/lane; LDS dest = wave-uniform base + lane*16.
  __builtin_amdgcn_global_load_lds((cv_g*)g, (v_l*)l, 16, 0, 0);
}

// perm dtype flag (fallback path only): 1 if int64, 0 if int32.
__device__ int g_perm_is64;

__global__ void decode_flag(const void* __restrict__ perm_raw) {
  if (threadIdx.x == 0 && blockIdx.x == 0) {
    const int* w = (const int*)perm_raw;
    int ok = 1;
    for (int j = 0; j < 32; ++j) {
      int lo = w[2 * j], hi = w[2 * j + 1];
      if (hi != 0 || lo < 0 || lo >= IN_F) { ok = 0; break; }
    }
    g_perm_is64 = ok;
  }
}

// Fused preprocessing (unchanged from R3 -- verified):
//   blocks [0, 2048):     xp[m, j] = bf16( x[m, perm[j]] )  (LDS-staged row gather)
//   blocks [2048, 10240): wf[o, k] = bf16( w_q[o,k] * s_w[k/128, o] )
__global__ __launch_bounds__(256) void prep(const float* __restrict__ x,
                                            const int* __restrict__ w_q,
                                            const float* __restrict__ s_w,
                                            const void* __restrict__ perm_raw,
                                            __hip_bfloat16* __restrict__ xp,
                                            __hip_bfloat16* __restrict__ wf) {
  __shared__ float sx[IN_F];
  __shared__ int sflag;
  const int b = blockIdx.x;
  const int t = threadIdx.x;

  if (b < M_ROWS) {
    const int m = b;
    const float* xr = x + (size_t)m * IN_F;
#pragma unroll
    for (int u = 0; u < 4; ++u) {
      int idx = (u * 256 + t) * 4;
      *(float4*)&sx[idx] = *(const float4*)&xr[idx];
    }
    if (t < 64) {
      const int* w = (const int*)perm_raw;
      int j = t & 31;  // lanes 32..63 duplicate 0..31 -> same ballot bits
      int lo = w[2 * j], hi = w[2 * j + 1];
      // int64 LE values in [0,4096): hi word always 0. int32 perm: w[2j+1] is a
      // perm value, ==0 for at most one j -> ballot never all-ones.
      int cond = (hi == 0 && lo >= 0 && lo < IN_F);
      unsigned long long bal = __ballot(cond);
      if (t == 0) sflag = (bal == ~0ull) ? 1 : 0;
    }
    __syncthreads();
    const int f = sflag;
    const long long* p64 = (const long long*)perm_raw;
    const int*       p32 = (const int*)perm_raw;
    const int jb = t * 16;
    __hip_bfloat16 tmp[16] __attribute__((aligned(16)));
#pragma unroll
    for (int u = 0; u < 16; ++u) {
      int pj = f ? (int)p64[jb + u] : p32[jb + u];
      tmp[u] = __float2bfloat16(sx[pj]);
    }
    *(uint4*)(xp + (size_t)m * IN_F + jb)     = *(const uint4*)&tmp[0];
    *(uint4*)(xp + (size_t)m * IN_F + jb + 8) = *(const uint4*)&tmp[8];
  } else {
    int tt = (b - M_ROWS) * 256 + t;
    int o  = tt >> 9;
    int kb = (tt & 511) << 3;
    float s = s_w[(size_t)(kb >> 7) * OUT_F + o];
    const int* wr = w_q + (size_t)o * IN_F + kb;
    int4 w0 = *(const int4*)wr;
    int4 w1 = *(const int4*)(wr + 4);
    __hip_bfloat16 tmp[8] __attribute__((aligned(16)));
    tmp[0] = __float2bfloat16((float)w0.x * s);
    tmp[1] = __float2bfloat16((float)w0.y * s);
    tmp[2] = __float2bfloat16((float)w0.z * s);
    tmp[3] = __float2bfloat16((float)w0.w * s);
    tmp[4] = __float2bfloat16((float)w1.x * s);
    tmp[5] = __float2bfloat16((float)w1.y * s);
    tmp[6] = __float2bfloat16((float)w1.z * s);
    tmp[7] = __float2bfloat16((float)w1.w * s);
    *(uint4*)(wf + (size_t)o * IN_F + kb) = *(const uint4*)tmp;
  }
}

// C[m,o] = sum_k A[m,k]*B[o,k] + bias[o]; A: M x K bf16, B: N x K bf16.
// R7: LDS-BW attack. Block 128x256, 512 thr = 8 waves: 2x2 spatial x 2 K-split.
// Wave tile 64x128 as 4x8 of 16x16x32 over its 32-wide K half.
// LDS reads drop to 12 KB / 0.52 MFLOP per wave-step (22.9 B/kFLOP, -25% vs
// the 64x64 wave tile). BK=64 double-buffered: 96 KB LDS -> 1 block/CU,
// 2 waves/SIMD. Grid 16x16 = 256 = 1 block/CU.
// LDS layout: chunk(row,kc) at row*8 + (kc ^ (row&7)) (verified 0-conflict
// family); staging = 8-lane groups covering contiguous 128B global segments.
// Epilogue: K-split partial sums reduced via LDS in two 64 KB rounds.
__global__ __launch_bounds__(512, 2) void gemm_bt(
    const __hip_bfloat16* __restrict__ A,
    const __hip_bfloat16* __restrict__ B,
    const float* __restrict__ bias,
    float* __restrict__ C) {
  // [buf0 | buf1], each: A 128x64 (8192 elems) then B 256x64 (16384 elems)
  __shared__ __hip_bfloat16 smem[49152];  // 96 KB

  const int tid  = threadIdx.x;
  const int w    = tid >> 6;        // 0..7
  const int lane = tid & 63;
  const int wr   = w >> 2;          // spatial row 0..1 (64-row slab)
  const int wc   = (w >> 1) & 1;    // spatial col 0..1 (128-col slab)
  const int kv   = w & 1;           // K-split half 0..1
  const int bm = blockIdx.y << 7;   // 128-row block
  const int bn = blockIdx.x << 8;   // 256-col block
  const int lrow = lane & 15;
  const int quad = lane >> 4;

  f32x4 acc[4][8] = {};

  // Staging: 3072 chunks of 16B (A: 1024, B: 2048); chunk c = h*512 + w*64 + lane,
  // h=0,1 -> A (row=c>>3), h=2..5 -> B (row=(c-1024)>>3); kc = (c&7) ^ (row&7).
  const __hip_bfloat16* gp[6];
  int lbase[6];
#pragma unroll
  for (int h = 0; h < 6; ++h) {
    int c = h * 512 + w * 64 + lane;
    if (c < 1024) {
      int row = c >> 3;
      int kc  = (c & 7) ^ (row & 7);
      gp[h] = A + (size_t)(bm + row) * IN_F + kc * 8;
      lbase[h] = (h * 512 + w * 64) * 8;            // A region, wave-uniform
    } else {
      int cb  = c - 1024;
      int row = cb >> 3;
      int kc  = (cb & 7) ^ (row & 7);
      gp[h] = B + (size_t)(bn + row) * IN_F + kc * 8;
      lbase[h] = 8192 + ((h - 2) * 512 + w * 64) * 8;  // B region, wave-uniform
    }
  }

  auto stage = [&](int bufofs, int kn) {
#pragma unroll
    for (int h = 0; h < 6; ++h)
      async16(gp[h] + kn, &smem[bufofs + lbase[h]]);
  };

  // Fragment addressing (elements, within buffer): this wave's k-chunk index
  // kc = kv*4 + quad; swizzled position = kc ^ (row&7).
  const int kc_log = (kv << 2) + quad;
  auto compute = [&](int bufofs) {
    bf16x8 af[4];
#pragma unroll
    for (int i = 0; i < 4; ++i) {
      int row = (wr << 6) + i * 16 + lrow;
      af[i] = *(const bf16x8*)&smem[bufofs + row * 64 + (kc_log ^ (row & 7)) * 8];
    }
#pragma unroll
    for (int j = 0; j < 8; ++j) {
      int rowb = (wc << 7) + j * 16 + lrow;
      bf16x8 bfr = *(const bf16x8*)&smem[bufofs + 8192 + rowb * 64 + (kc_log ^ (rowb & 7)) * 8];
#pragma unroll
      for (int i = 0; i < 4; ++i)
        acc[i][j] = __builtin_amdgcn_mfma_f32_16x16x32_bf16(af[i], bfr, acc[i][j], 0, 0, 0);
    }
  };

  stage(0, 0);  // prologue
  for (int k0 = 0; k0 < IN_F; k0 += 128) {
    __syncthreads();                       // buf0@k0 visible; reads of buf1 done
    stage(24576, k0 + 64);                 // k0+64 <= 4032, always valid
    compute(0);
    __syncthreads();                       // buf1@k0+64 visible; reads of buf0 done
    if (k0 + 128 < IN_F) stage(0, k0 + 128);
    compute(24576);
  }

  // Epilogue: K-split reduce via LDS (two rounds of 64 KB), then bias + store.
  // C/D layout col=lane&15, row=quad*4+reg  [measured m89/m91].
  float* red = (float*)&smem[0];  // reuse LDS: 2 spatial cols x 64x128 f32 = 64 KB
#pragma unroll
  for (int t = 0; t < 2; ++t) {
    __syncthreads();
    if (wr == t && kv == 1) {
      float* dst = red + wc * 8192;  // 64 rows x 128 cols
#pragma unroll
      for (int i = 0; i < 4; ++i)
#pragma unroll
        for (int j = 0; j < 8; ++j)
#pragma unroll
          for (int r = 0; r < 4; ++r)
            dst[(i * 16 + quad * 4 + r) * 128 + j * 16 + lrow] = acc[i][j][r];
    }
    __syncthreads();
    if (wr == t && kv == 0) {
      const float* src = red + wc * 8192;
#pragma unroll
      for (int i = 0; i < 4; ++i) {
        int row = bm + (wr << 6) + i * 16 + quad * 4;
#pragma unroll
        for (int j = 0; j < 8; ++j) {
          int col = bn + (wc << 7) + j * 16 + lrow;
          float bv = bias[col];
#pragma unroll
          for (int r = 0; r < 4; ++r)
            C[(size_t)(row + r) * OUT_F + col] =
                acc[i][j][r] + src[(i * 16 + quad * 4 + r) * 128 + j * 16 + lrow] + bv;
        }
      }
    }
  }
}

// Correct-but-slow fp32 fallback if workspace is too small for bf16 staging.
__global__ void naive_fallback(const float* __restrict__ x, const int* __restrict__ w_q,
                               const float* __restrict__ s_w, const void* __restrict__ perm_raw,
                               const float* __restrict__ bias, float* __restrict__ out) {
  int t = blockIdx.x * blockDim.x + threadIdx.x;
  int m = t >> 12;
  int o = t & 4095;
  const int f = g_perm_is64;
  const long long* p64 = (const long long*)perm_raw;
  const int*       p32 = (const int*)perm_raw;
  const float* xr = x + (size_t)m * IN_F;
  const int*   wr = w_q + (size_t)o * IN_F;
  float acc = 0.f;
  for (int g = 0; g < NG; ++g) {
    float part = 0.f;
    for (int k = 0; k < GRP; ++k) {
      int j = g * GRP + k;
      int pj = f ? (int)p64[j] : p32[j];
      part += xr[pj] * (float)wr[j];
    }
    acc += part * s_w[(size_t)g * OUT_F + o];
  }
  out[t] = acc + bias[o];
}

extern "C" void kernel_launch(void* const* d_in, const int* in_sizes, int n_in,
                              void* d_out, int out_size, void* d_ws, size_t ws_size,
                              hipStream_t stream) {
  const float* x    = (const float*)d_in[0];
  const int*   w_q  = (const int*)d_in[1];
  const float* s_w  = (const float*)d_in[2];
  const void*  perm = d_in[3];   // int64 or int32 -- detected on device
  const float* bias = (const float*)d_in[4];
  float* out = (float*)d_out;

  const size_t xp_bytes = (size_t)M_ROWS * IN_F * sizeof(__hip_bfloat16);  // 16 MiB
  const size_t wf_bytes = (size_t)OUT_F * IN_F * sizeof(__hip_bfloat16);   // 32 MiB

  if (ws_size < xp_bytes + wf_bytes) {
    decode_flag<<<1, 64, 0, stream>>>(perm);
    naive_fallback<<<(M_ROWS * OUT_F) / 256, 256, 0, stream>>>(x, w_q, s_w, perm, bias, out);
    return;
  }

  __hip_bfloat16* xp = (__hip_bfloat16*)d_ws;
  __hip_bfloat16* wf = (__hip_bfloat16*)((char*)d_ws + xp_bytes);

  prep<<<M_ROWS + (OUT_F * IN_F / 8) / 256, 256, 0, stream>>>(x, w_q, s_w, perm, xp, wf);

  dim3 grid(OUT_F / 256, M_ROWS / 128);  // 16 x 16 = 256 blocks, 1/CU
  gemm_bt<<<grid, 512, 0, stream>>>(xp, wf, bias, out);
}

// Round 8
// 195.366 us; speedup vs baseline: 1.1230x; 1.1230x over previous
//
#include <hip/hip_runtime.h>
#include <hip/hip_bf16.h>
#include <stdint.h>

#define IN_F   4096
#define OUT_F  4096
#define M_ROWS 2048
#define NG     32
#define GRP    128

typedef int   v4i  __attribute__((ext_vector_type(4)));
typedef float f32x4 __attribute__((ext_vector_type(4)));

typedef const void __attribute__((address_space(1))) cv_g;
typedef void       __attribute__((address_space(3))) v_l;

__device__ __forceinline__ void async16(const void* g, void* l) {
  // global -> LDS DMA, 16B/lane; LDS dest = wave-uniform base + lane*16.
  __builtin_amdgcn_global_load_lds((cv_g*)g, (v_l*)l, 16, 0, 0);
}

// perm dtype flag (fallback path only): 1 if int64, 0 if int32.
__device__ int g_perm_is64;

__global__ void decode_flag(const void* __restrict__ perm_raw) {
  if (threadIdx.x == 0 && blockIdx.x == 0) {
    const int* w = (const int*)perm_raw;
    int ok = 1;
    for (int j = 0; j < 32; ++j) {
      int lo = w[2 * j], hi = w[2 * j + 1];
      if (hi != 0 || lo < 0 || lo >= IN_F) { ok = 0; break; }
    }
    g_perm_is64 = ok;
  }
}

// Fused preprocessing (int8 edition):
//   blocks [0, 2048):    gather row m, quantize to int8 with per-ROW scale:
//                        xq[m,j] = rint( x[m,perm[j]] * 127/max|row| ), sxr[m]=max/127
//   blocks [2048, 6144): pack w_q int32 -> int8 (values already in [-128,127], exact)
__global__ __launch_bounds__(256) void prep(const float* __restrict__ x,
                                            const int* __restrict__ w_q,
                                            const void* __restrict__ perm_raw,
                                            char* __restrict__ xq,
                                            char* __restrict__ w8,
                                            float* __restrict__ sxr) {
  __shared__ float sx[IN_F];
  __shared__ float red[4];
  __shared__ int sflag;
  const int b = blockIdx.x;
  const int t = threadIdx.x;

  if (b < M_ROWS) {
    const int m = b;
    const float* xr = x + (size_t)m * IN_F;
#pragma unroll
    for (int u = 0; u < 4; ++u) {
      int idx = (u * 256 + t) * 4;
      *(float4*)&sx[idx] = *(const float4*)&xr[idx];
    }
    if (t < 64) {
      const int* w = (const int*)perm_raw;
      int j = t & 31;  // lanes 32..63 duplicate 0..31 -> same ballot bits
      int lo = w[2 * j], hi = w[2 * j + 1];
      // int64 LE values in [0,4096): hi word always 0. int32 perm: w[2j+1] is a
      // perm value, ==0 for at most one j -> ballot never all-ones.
      int cond = (hi == 0 && lo >= 0 && lo < IN_F);
      unsigned long long bal = __ballot(cond);
      if (t == 0) sflag = (bal == ~0ull) ? 1 : 0;
    }
    __syncthreads();
    const int f = sflag;
    const long long* p64 = (const long long*)perm_raw;
    const int*       p32 = (const int*)perm_raw;
    const int jb = t * 16;
    float vals[16];
    float lmax = 0.f;
#pragma unroll
    for (int u = 0; u < 16; ++u) {
      int pj = f ? (int)p64[jb + u] : p32[jb + u];
      float v = sx[pj];
      vals[u] = v;
      lmax = fmaxf(lmax, fabsf(v));
    }
    // row max: wave shuffle-reduce then cross-wave via LDS
#pragma unroll
    for (int d = 1; d < 64; d <<= 1)
      lmax = fmaxf(lmax, __shfl_xor(lmax, d, 64));
    if ((t & 63) == 0) red[t >> 6] = lmax;
    __syncthreads();
    float rmax = fmaxf(fmaxf(red[0], red[1]), fmaxf(red[2], red[3]));
    float inv = (rmax > 0.f) ? 127.f / rmax : 0.f;
    if (t == 0) sxr[m] = rmax / 127.f;
    char q[16] __attribute__((aligned(16)));
#pragma unroll
    for (int u = 0; u < 16; ++u)
      q[u] = (char)__float2int_rn(vals[u] * inv);
    *(uint4*)(xq + (size_t)m * IN_F + jb) = *(const uint4*)q;
  } else {
    // pack weights: one block per output row o; thread t -> 16 consecutive k
    const int o  = b - M_ROWS;
    const int kb = t * 16;
    const int* wr = w_q + (size_t)o * IN_F + kb;
    int4 w0 = *(const int4*)(wr + 0);
    int4 w1 = *(const int4*)(wr + 4);
    int4 w2 = *(const int4*)(wr + 8);
    int4 w3 = *(const int4*)(wr + 12);
    char q[16] __attribute__((aligned(16)));
    q[0]=(char)w0.x; q[1]=(char)w0.y; q[2]=(char)w0.z; q[3]=(char)w0.w;
    q[4]=(char)w1.x; q[5]=(char)w1.y; q[6]=(char)w1.z; q[7]=(char)w1.w;
    q[8]=(char)w2.x; q[9]=(char)w2.y; q[10]=(char)w2.z; q[11]=(char)w2.w;
    q[12]=(char)w3.x; q[13]=(char)w3.y; q[14]=(char)w3.z; q[15]=(char)w3.w;
    *(uint4*)(w8 + (size_t)o * IN_F + kb) = *(const uint4*)q;
  }
}

// C[m,o] = sxr[m] * sum_g s_w[g,o] * (int8 dot over group g) + bias[o]
// R8: int8 MFMA. 128x128 tile, BK=128 (= one scale group) double-buffered:
// per buf A 16 KB + B 16 KB; 2 bufs + s_w block (bf16, 8 KB) = 72 KB LDS
// -> 2 blocks/CU (the R7 lesson: co-residency is mandatory).
// Same verified 16B-chunk geometry as R5: chunk(row,kc) at row*8 + (kc^(row&7)),
// staging 8-lane groups cover one contiguous 128B global segment, fragment
// reads 2-way-bank-aliased (free). 32 K-iters, 2 barriers each.
// Integer dots are exact; per-group rescale accf += sw[g,col]*(float)acci.
__global__ __launch_bounds__(256, 2) void gemm_i8(
    const char* __restrict__ A,     // xq  M x K int8
    const char* __restrict__ B,     // w8  N x K int8
    const float* __restrict__ s_w,  // NG x OUT_F
    const float* __restrict__ sxr,  // M
    const float* __restrict__ bias,
    float* __restrict__ C) {
  __shared__ char smem[2][32768];           // per buf: A 16384 | B 16384 bytes
  __shared__ unsigned short sws[NG * 128];  // s_w for this block's 128 cols, bf16

  const int tid  = threadIdx.x;
  const int wave = tid >> 6;
  const int lane = tid & 63;
  const int bm = blockIdx.y << 7;
  const int bn = blockIdx.x << 7;
  const int wm = (wave >> 1) << 6;
  const int wn = (wave & 1) << 6;
  const int lrow = lane & 15;
  const int quad = lane >> 4;

  // stage s_w block into LDS as bf16 (keeps the K-loop free of global loads,
  // so the DMA vmcnt queue is never drained mid-iter)
#pragma unroll
  for (int u = 0; u < 16; ++u) {
    int idx = u * 256 + tid;               // [g][c], c = local col
    int g = idx >> 7, c = idx & 127;
    __hip_bfloat16 h = __float2bfloat16(s_w[(size_t)g * OUT_F + bn + c]);
    sws[idx] = *(unsigned short*)&h;
  }

  f32x4 accf[4][4] = {};

  // Staging: per buf 2048 chunks of 16B. Round r = h*4+wave (h=0..7) covers
  // chunks c = r*64 + lane. c<1024 -> A (row=c>>3), else B. kc = (c&7)^(row&7).
  const char* gp[8];
  int lofs[8];
#pragma unroll
  for (int h = 0; h < 8; ++h) {
    int c0 = (h * 4 + wave) * 64;
    int c  = c0 + lane;
    if (c < 1024) {
      int row = c >> 3;
      int kc  = (c & 7) ^ (row & 7);
      gp[h]   = A + (size_t)(bm + row) * IN_F + kc * 16;
      lofs[h] = c0 * 16;
    } else {
      int cb  = c - 1024;
      int row = cb >> 3;
      int kc  = (cb & 7) ^ (row & 7);
      gp[h]   = B + (size_t)(bn + row) * IN_F + kc * 16;
      lofs[h] = 16384 + (c0 - 1024) * 16;
    }
  }

  auto stage = [&](int p, int kn) {
#pragma unroll
    for (int h = 0; h < 8; ++h)
      async16(gp[h] + kn, &smem[p][lofs[h]]);
  };

  auto compute = [&](int p, int g) {
    const char* bufA = smem[p];
    const char* bufB = smem[p] + 16384;
    v4i acci[4][4] = {};
#pragma unroll
    for (int s = 0; s < 2; ++s) {
      v4i af[4], bf[4];
#pragma unroll
      for (int i = 0; i < 4; ++i) {
        int row = wm + i * 16 + lrow;
        af[i] = *(const v4i*)&bufA[row * 128 + (((s << 2) + quad) ^ (row & 7)) * 16];
      }
#pragma unroll
      for (int j = 0; j < 4; ++j) {
        int row = wn + j * 16 + lrow;
        bf[j] = *(const v4i*)&bufB[row * 128 + (((s << 2) + quad) ^ (row & 7)) * 16];
      }
#pragma unroll
      for (int i = 0; i < 4; ++i)
#pragma unroll
        for (int j = 0; j < 4; ++j)
          acci[i][j] = __builtin_amdgcn_mfma_i32_16x16x64_i8(af[i], bf[j], acci[i][j], 0, 0, 0);
    }
    // per-group rescale (exact int32 -> f32, scaled by s_w[g, col])
    float swv[4];
#pragma unroll
    for (int j = 0; j < 4; ++j) {
      unsigned int u = sws[g * 128 + wn + j * 16 + lrow];
      swv[j] = __uint_as_float(u << 16);
    }
#pragma unroll
    for (int i = 0; i < 4; ++i)
#pragma unroll
      for (int j = 0; j < 4; ++j)
#pragma unroll
        for (int r = 0; r < 4; ++r)
          accf[i][j][r] += swv[j] * (float)acci[i][j][r];
  };

  stage(0, 0);  // prologue
  for (int k0 = 0; k0 < IN_F; k0 += 256) {
    __syncthreads();                       // buf0@k0 visible; reads of buf1 done
    stage(1, k0 + 128);                    // k0+128 <= 3968, always valid
    compute(0, k0 >> 7);
    __syncthreads();                       // buf1 visible; reads of buf0 done
    if (k0 + 256 < IN_F) stage(0, k0 + 256);
    compute(1, (k0 >> 7) + 1);
  }

  // Epilogue: C/D layout col=lane&15, row=quad*4+reg (dtype-independent,
  // m89/m121-128). Apply per-row x-scale + bias.
#pragma unroll
  for (int i = 0; i < 4; ++i) {
    int r0 = bm + wm + i * 16 + quad * 4;
    float sxv[4];
#pragma unroll
    for (int r = 0; r < 4; ++r) sxv[r] = sxr[r0 + r];  // quad-broadcast loads
#pragma unroll
    for (int j = 0; j < 4; ++j) {
      int col = bn + wn + j * 16 + lrow;
      float bv = bias[col];
#pragma unroll
      for (int r = 0; r < 4; ++r)
        C[(size_t)(r0 + r) * OUT_F + col] = sxv[r] * accf[i][j][r] + bv;
    }
  }
}

// Correct-but-slow fp32 fallback if workspace is too small.
__global__ void naive_fallback(const float* __restrict__ x, const int* __restrict__ w_q,
                               const float* __restrict__ s_w, const void* __restrict__ perm_raw,
                               const float* __restrict__ bias, float* __restrict__ out) {
  int t = blockIdx.x * blockDim.x + threadIdx.x;
  int m = t >> 12;
  int o = t & 4095;
  const int f = g_perm_is64;
  const long long* p64 = (const long long*)perm_raw;
  const int*       p32 = (const int*)perm_raw;
  const float* xr = x + (size_t)m * IN_F;
  const int*   wr = w_q + (size_t)o * IN_F;
  float acc = 0.f;
  for (int g = 0; g < NG; ++g) {
    float part = 0.f;
    for (int k = 0; k < GRP; ++k) {
      int j = g * GRP + k;
      int pj = f ? (int)p64[j] : p32[j];
      part += xr[pj] * (float)wr[j];
    }
    acc += part * s_w[(size_t)g * OUT_F + o];
  }
  out[t] = acc + bias[o];
}

extern "C" void kernel_launch(void* const* d_in, const int* in_sizes, int n_in,
                              void* d_out, int out_size, void* d_ws, size_t ws_size,
                              hipStream_t stream) {
  const float* x    = (const float*)d_in[0];
  const int*   w_q  = (const int*)d_in[1];
  const float* s_w  = (const float*)d_in[2];
  const void*  perm = d_in[3];   // int64 or int32 -- detected on device
  const float* bias = (const float*)d_in[4];
  float* out = (float*)d_out;

  const size_t xq_bytes = (size_t)M_ROWS * IN_F;            // 8 MiB int8
  const size_t w8_bytes = (size_t)OUT_F * IN_F;             // 16 MiB int8
  const size_t sx_bytes = (size_t)M_ROWS * sizeof(float);   // 8 KiB
  const size_t need = xq_bytes + w8_bytes + sx_bytes;

  if (ws_size < need) {
    decode_flag<<<1, 64, 0, stream>>>(perm);
    naive_fallback<<<(M_ROWS * OUT_F) / 256, 256, 0, stream>>>(x, w_q, s_w, perm, bias, out);
    return;
  }

  char*  xq  = (char*)d_ws;
  char*  w8  = (char*)d_ws + xq_bytes;
  float* sxr = (float*)((char*)d_ws + xq_bytes + w8_bytes);

  prep<<<M_ROWS + OUT_F, 256, 0, stream>>>(x, w_q, perm, xq, w8, sxr);

  dim3 grid(OUT_F / 128, M_ROWS / 128);  // 32 x 16 = 512 blocks, 2/CU
  gemm_i8<<<grid, 256, 0, stream>>>(xq, w8, s_w, sxr, bias, out);
}